// Round 14
// baseline (576.738 us; speedup 1.0000x reference)
//
#include <hip/hip_runtime.h>
#include <hip/hip_bf16.h>

// DimeNet-like GNN, f32 in/out. Round 13: MEASUREMENT A/B. Identical to
// round 12 (388us best) except:
//  (1) the 3-layer loop runs TWICE (2nd pass restarts from x; deterministic,
//      output identical). Marginal cost D = dur-388 isolates per-layer
//      kernels+gaps from fixed harness overhead. D small => harness floor.
//  (2) k_setup's dtype probe parallelized (was a 256-deep serial load chain
//      in one thread).

#define N_NODES 16000
#define N_EDGES 256000
#define N_TRI   640000
#define N_B     128
#define OUT_DIM 32
#define L_LAYERS 3

typedef __hip_bfloat16 bf16;
typedef short s8v __attribute__((ext_vector_type(8)));
typedef float f4v __attribute__((ext_vector_type(4)));

#define NTS(p, v) __builtin_nontemporal_store((v), (p))

__device__ __forceinline__ float ldx(const void* p, size_t i, int f) {
    if (f) return ((const float*)p)[i];
    return __bfloat162float(((const bf16*)p)[i]);
}

__device__ __forceinline__ unsigned short f2bf_rne(float x) {
    unsigned int u = __float_as_uint(x);
    unsigned int r = (u + 0x7FFFu + ((u >> 16) & 1u)) >> 16;
    return (unsigned short)r;
}
__device__ __forceinline__ float bf2f(unsigned short b) {
    return __uint_as_float(((unsigned int)b) << 16);
}
__device__ __forceinline__ void split2(float a, unsigned short& h, unsigned short& l) {
    h = f2bf_rne(a);
    l = f2bf_rne(a - bf2f(h));
}
__device__ __forceinline__ void make_afrag(const float* av, s8v& ah, s8v& al) {
    #pragma unroll
    for (int j = 0; j < 8; j++) {
        unsigned short h, l; split2(av[j], h, l);
        ah[j] = (short)h; al[j] = (short)l;
    }
}

__device__ __forceinline__ void stageW(const void* W, size_t offW, int KS, int f,
                                       unsigned short* sBhi, unsigned short* sBlo) {
    for (int idx = threadIdx.x; idx < KS * 2048; idx += 256) {
        int jj = idx & 7, ln = (idx >> 3) & 63, nt = (idx >> 9) & 3, ks = idx >> 11;
        int k = ks * 32 + (ln >> 4) * 8 + jj;
        int n = nt * 16 + (ln & 15);
        float w = ldx(W, offW + (size_t)k * 64 + n, f);
        unsigned short h_, l_; split2(w, h_, l_);
        sBhi[idx] = h_; sBlo[idx] = l_;
    }
}

__device__ __forceinline__ void mfma3(const unsigned short* sBhi, const unsigned short* sBlo,
                                      int ks, int lane, const s8v& ah, const s8v& al,
                                      f4v acc[4]) {
    #pragma unroll
    for (int nt = 0; nt < 4; nt++) {
        s8v bh = *(const s8v*)&sBhi[(ks * 4 + nt) * 512 + lane * 8];
        s8v bl = *(const s8v*)&sBlo[(ks * 4 + nt) * 512 + lane * 8];
        acc[nt] = __builtin_amdgcn_mfma_f32_16x16x32_bf16(ah, bh, acc[nt], 0, 0, 0);
        acc[nt] = __builtin_amdgcn_mfma_f32_16x16x32_bf16(al, bh, acc[nt], 0, 0, 0);
        acc[nt] = __builtin_amdgcn_mfma_f32_16x16x32_bf16(ah, bl, acc[nt], 0, 0, 0);
    }
}

__device__ __forceinline__ void ldrow8(const void* A, int fa, size_t row, int ks,
                                       int quad, float av[8]) {
    if (fa) {
        const float* p = (const float*)A + row * 64 + ks * 32 + quad * 8;
        float4 x0 = ((const float4*)p)[0], x1 = ((const float4*)p)[1];
        av[0] = x0.x; av[1] = x0.y; av[2] = x0.z; av[3] = x0.w;
        av[4] = x1.x; av[5] = x1.y; av[6] = x1.z; av[7] = x1.w;
    } else {
        const bf16* p = (const bf16*)A + row * 64 + ks * 32 + quad * 8;
        #pragma unroll
        for (int j = 0; j < 8; j++) av[j] = __bfloat162float(p[j]);
    }
}

// ---------------------------------------------------------------- diag helpers
__global__ void k_probe(const void* __restrict__ rbf, int* __restrict__ flag) {
    if (threadIdx.x == 0 && blockIdx.x == 0) {
        const float* p = (const float*)rbf;
        int good = 0;
        for (int i = 0; i < 256; i++) {
            float v = fabsf(p[i]);
            if (v > 1e-4f && v < 100.0f) good++;
        }
        *flag = (good > 192) ? 1 : 0;
    }
}
__global__ void k_fill(void* __restrict__ out, const int* __restrict__ flag,
                       float val, int n) {
    int i = blockIdx.x * blockDim.x + threadIdx.x;
    if (i < n) {
        if (*flag) ((float*)out)[i] = val;
        else       ((bf16*)out)[i] = __float2bfloat16(val);
    }
}

// ---------------------------------------------------------------- setup (parallel probe)
__global__ void k_setup(const void* __restrict__ rbf, int* __restrict__ flag,
                        int* __restrict__ cur) {
    int i = blockIdx.x * blockDim.x + threadIdx.x;
    int stride = gridDim.x * blockDim.x;
    for (; i < 2 * N_NODES; i += stride) cur[i] = 0;
    if (blockIdx.x == 0 && threadIdx.x < 64) {
        const float* p = (const float*)rbf;
        int good = 0;
        #pragma unroll
        for (int q = 0; q < 4; q++) {
            float v = fabsf(p[threadIdx.x * 4 + q]);
            if (v > 1e-4f && v < 100.0f) good++;
        }
        #pragma unroll
        for (int d = 1; d < 64; d <<= 1)
            good += __shfl_xor(good, d);
        if (threadIdx.x == 0) *flag = (good > 192) ? 1 : 0;
    }
}

__global__ void k_hist2(const int* __restrict__ j_idx, const int* __restrict__ edge_index,
                        int* __restrict__ cur_t, int* __restrict__ cur_e) {
    const int TB = (N_TRI + 255) / 256;
    if ((int)blockIdx.x < TB) {
        int i = blockIdx.x * 256 + threadIdx.x;
        if (i < N_TRI) {
            unsigned j = (unsigned)j_idx[i];
            if (j < N_NODES) atomicAdd(&cur_t[j], 1);
        }
    } else {
        int i = (blockIdx.x - TB) * 256 + threadIdx.x;
        if (i < N_EDGES) {
            unsigned d = (unsigned)edge_index[N_EDGES + i];
            if (d < N_NODES) atomicAdd(&cur_e[d], 1);
        }
    }
}

__global__ __launch_bounds__(256) void k_scan2(int* __restrict__ a, int* __restrict__ b) {
    int* cnt = (blockIdx.x == 0) ? a : b;
    __shared__ int part[256];
    int tid = threadIdx.x;
    const int PER = (N_NODES + 255) / 256;
    int base = tid * PER;
    int s = 0;
    for (int i = 0; i < PER; i++) {
        int idx = base + i;
        if (idx < N_NODES) s += cnt[idx];
    }
    part[tid] = s;
    __syncthreads();
    for (int d = 1; d < 256; d <<= 1) {
        int v = (tid >= d) ? part[tid - d] : 0;
        __syncthreads();
        part[tid] += v;
        __syncthreads();
    }
    int run = (tid > 0) ? part[tid - 1] : 0;
    for (int i = 0; i < PER; i++) {
        int idx = base + i;
        if (idx < N_NODES) {
            int v = cnt[idx];
            cnt[idx] = run;
            run += v;
        }
    }
}

__global__ void k_scatter2(const int* __restrict__ j_idx, const int* __restrict__ k_idx,
                           const int* __restrict__ edge_index,
                           int* __restrict__ cur_t, int* __restrict__ cur_e,
                           int* __restrict__ tri_o, int* __restrict__ k_srt,
                           int* __restrict__ src_s) {
    const int TB = (N_TRI + 255) / 256;
    if ((int)blockIdx.x < TB) {
        int i = blockIdx.x * 256 + threadIdx.x;
        if (i < N_TRI) {
            unsigned j = (unsigned)j_idx[i];
            if (j < N_NODES) {
                int pos = atomicAdd(&cur_t[j], 1);
                if ((unsigned)pos < (unsigned)N_TRI) {
                    unsigned k = (unsigned)k_idx[i]; if (k >= N_NODES) k = 0;
                    tri_o[pos] = i;
                    k_srt[pos] = (int)k;
                }
            }
        }
    } else {
        int e = (blockIdx.x - TB) * 256 + threadIdx.x;
        if (e < N_EDGES) {
            unsigned d = (unsigned)edge_index[N_EDGES + e];
            if (d < N_NODES) {
                int pos = atomicAdd(&cur_e[d], 1);
                if ((unsigned)pos < (unsigned)N_EDGES) {
                    unsigned s = (unsigned)edge_index[e]; if (s >= N_NODES) s = 0;
                    src_s[pos] = (int)s;
                }
            }
        }
    }
}

// ---------------------------------------------------------------- lin2out
__global__ __launch_bounds__(256) void k_lin2out(
    const void* __restrict__ A1, int a1ws,
    const void* __restrict__ W1, size_t offW1, const void* __restrict__ b1,
    const void* __restrict__ W2, size_t offW2, const void* __restrict__ b2,
    size_t offB, const int* __restrict__ flag,
    float* __restrict__ X, float* __restrict__ Y) {
    __shared__ unsigned short h1[2 * 2048], l1[2 * 2048];
    __shared__ unsigned short h2[2 * 2048], l2[2 * 2048];
    __shared__ float sB1[64], sB2[64];
    int f = *flag;
    int fa = a1ws ? 1 : f;
    stageW(W1, offW1, 2, f, h1, l1);
    stageW(W2, offW2, 2, f, h2, l2);
    if (threadIdx.x < 64) {
        sB1[threadIdx.x] = ldx(b1, offB + threadIdx.x, f);
        sB2[threadIdx.x] = ldx(b2, offB + threadIdx.x, f);
    }
    __syncthreads();
    int lane = threadIdx.x & 63;
    int quad = lane >> 4;
    int m = lane & 15;
    int tile = blockIdx.x * 4 + (threadIdx.x >> 6);
    size_t row = (size_t)tile * 16 + m;
    f4v accH[4], accS[4];
    #pragma unroll
    for (int nt = 0; nt < 4; nt++) {
        float bh = sB1[nt * 16 + m], bs = sB2[nt * 16 + m];
        accH[nt] = (f4v){bh, bh, bh, bh};
        accS[nt] = (f4v){bs, bs, bs, bs};
    }
    float av[8]; s8v ah, al;
    #pragma unroll
    for (int ks = 0; ks < 2; ks++) {
        ldrow8(A1, fa, row, ks, quad, av);
        make_afrag(av, ah, al);
        mfma3(h1, l1, ks, lane, ah, al, accH);
        mfma3(h2, l2, ks, lane, ah, al, accS);
    }
    #pragma unroll
    for (int r = 0; r < 4; r++) {
        size_t rr = (size_t)(tile * 16 + quad * 4 + r) * 64 + m;
        #pragma unroll
        for (int nt = 0; nt < 4; nt++) {
            NTS(&X[rr + nt * 16], accH[nt][r]);
            NTS(&Y[rr + nt * 16], accS[nt][r]);
        }
    }
}

// ---------------------------------------------------------------- 64x64 linear (Ad)
__global__ __launch_bounds__(256) void k_lin1(
    const float* __restrict__ A, const void* __restrict__ W, size_t offW,
    const int* __restrict__ flag, float* __restrict__ out) {
    __shared__ unsigned short wh[2 * 2048], wl[2 * 2048];
    int f = *flag;
    stageW(W, offW, 2, f, wh, wl);
    __syncthreads();
    int lane = threadIdx.x & 63;
    int quad = lane >> 4;
    int m = lane & 15;
    int tile = blockIdx.x * 4 + (threadIdx.x >> 6);
    size_t row = (size_t)tile * 16 + m;
    f4v acc[4];
    #pragma unroll
    for (int nt = 0; nt < 4; nt++) acc[nt] = (f4v){0.f, 0.f, 0.f, 0.f};
    float av[8]; s8v ah, al;
    #pragma unroll
    for (int ks = 0; ks < 2; ks++) {
        ldrow8(A, 1, row, ks, quad, av);
        make_afrag(av, ah, al);
        mfma3(wh, wl, ks, lane, ah, al, acc);
    }
    #pragma unroll
    for (int r = 0; r < 4; r++) {
        size_t rr = (size_t)(tile * 16 + quad * 4 + r) * 64 + m;
        #pragma unroll
        for (int nt = 0; nt < 4; nt++)
            NTS(&out[rr + nt * 16], acc[nt][r]);
    }
}

// ---------------------------------------------------------------- tri segment sum
__global__ __launch_bounds__(256) void k_tri_seg(
    const int* __restrict__ ends, const int* __restrict__ tri_o,
    const int* __restrict__ k_srt, const float* __restrict__ Hh,
    const void* __restrict__ rbf, const void* __restrict__ cbf,
    const void* __restrict__ W1, size_t offW,
    const int* __restrict__ flag, float* __restrict__ agg_e) {
    int f = *flag;
    int c = threadIdx.x & 63;
    float wr[6], wc[6];
    #pragma unroll
    for (int q = 0; q < 6; q++) {
        wr[q] = ldx(W1, offW + (size_t)(64 + q) * 64 + c, f);
        wc[q] = ldx(W1, offW + (size_t)(70 + q) * 64 + c, f);
    }
    int j = blockIdx.x * 4 + (threadIdx.x >> 6);
    int p0 = (j == 0) ? 0 : ends[j - 1];
    int p1 = ends[j];
    if (p0 < 0) p0 = 0; if (p0 > N_TRI) p0 = N_TRI;
    if (p1 < p0) p1 = p0; if (p1 > N_TRI) p1 = N_TRI;
    float rb = 0.f;
    #pragma unroll
    for (int q = 0; q < 6; q++)
        rb += ldx(rbf, (size_t)j * 6 + q, f) * wr[q];
    float s = 0.f;
    for (int p = p0; p < p1; p += 4) {
        int tq[4], kq[4];
        float hv[4], cb[4][6];
        #pragma unroll
        for (int i = 0; i < 4; i++) {
            int ok = (p + i < p1);
            int t = ok ? tri_o[p + i] : -1;
            if ((unsigned)t >= N_TRI) t = -1;
            tq[i] = t;
            int k = ok ? k_srt[p + i] : 0;
            if ((unsigned)k >= N_NODES) k = 0;
            kq[i] = k;
        }
        #pragma unroll
        for (int i = 0; i < 4; i++)
            hv[i] = Hh[(size_t)kq[i] * 64 + c];
        #pragma unroll
        for (int i = 0; i < 4; i++) {
            if (tq[i] >= 0) {
                if (f) {
                    const float2* cp = (const float2*)((const float*)cbf + (size_t)tq[i] * 6);
                    float2 c0 = cp[0], c1 = cp[1], c2 = cp[2];
                    cb[i][0] = c0.x; cb[i][1] = c0.y; cb[i][2] = c1.x;
                    cb[i][3] = c1.y; cb[i][4] = c2.x; cb[i][5] = c2.y;
                } else {
                    #pragma unroll
                    for (int q = 0; q < 6; q++)
                        cb[i][q] = ldx(cbf, (size_t)tq[i] * 6 + q, 0);
                }
            }
        }
        #pragma unroll
        for (int i = 0; i < 4; i++) {
            if (tq[i] < 0) continue;
            float v = hv[i] + rb;
            #pragma unroll
            for (int q = 0; q < 6; q++)
                v += cb[i][q] * wc[q];
            s += fmaxf(v, 0.f);
        }
    }
    NTS(&agg_e[(size_t)j * 64 + c], s);
}

// ---------------------------------------------------------------- edge segment sum
__global__ __launch_bounds__(256) void k_edge_s(
    const int* __restrict__ ends, const int* __restrict__ src_s,
    const float* __restrict__ Hs, const float* __restrict__ Ad,
    float* __restrict__ aggr) {
    int c = threadIdx.x & 63;
    int d = blockIdx.x * 4 + (threadIdx.x >> 6);
    int p0 = (d == 0) ? 0 : ends[d - 1];
    int p1 = ends[d];
    if (p0 < 0) p0 = 0; if (p0 > N_EDGES) p0 = N_EDGES;
    if (p1 < p0) p1 = p0; if (p1 > N_EDGES) p1 = N_EDGES;
    float ad = Ad[(size_t)d * 64 + c];
    float s = 0.f;
    for (int p = p0; p < p1; p += 8) {
        int ss[8];
        float hv[8];
        #pragma unroll
        for (int i = 0; i < 8; i++) {
            int sv = (p + i < p1) ? src_s[p + i] : 0;
            if ((unsigned)sv >= N_NODES) sv = 0;
            ss[i] = sv;
        }
        #pragma unroll
        for (int i = 0; i < 8; i++)
            hv[i] = Hs[(size_t)ss[i] * 64 + c];
        #pragma unroll
        for (int i = 0; i < 8; i++)
            if (p + i < p1) s += fmaxf(hv[i] + ad, 0.f);
    }
    NTS(&aggr[(size_t)d * 64 + c], s);
}

// ---------------------------------------------------------------- fused node MLP
__global__ __launch_bounds__(256) void k_node_f(
    const void* __restrict__ A1, int a1ws, const float* __restrict__ aggr,
    const void* __restrict__ Wn1, const void* __restrict__ bn1,
    const void* __restrict__ Wn2, const void* __restrict__ bn2,
    size_t offW1, size_t offB, size_t offW2,
    const int* __restrict__ flag, float* __restrict__ hout) {
    __shared__ unsigned short s1h[4 * 2048], s1l[4 * 2048];
    __shared__ unsigned short s2h[2 * 2048], s2l[2 * 2048];
    __shared__ float sB1[64], sB2[64];
    __shared__ float zbuf[4][16 * 68];
    int f = *flag;
    int fa = a1ws ? 1 : f;
    stageW(Wn1, offW1, 4, f, s1h, s1l);
    stageW(Wn2, offW2, 2, f, s2h, s2l);
    if (threadIdx.x < 64) {
        sB1[threadIdx.x] = ldx(bn1, offB + threadIdx.x, f);
        sB2[threadIdx.x] = ldx(bn2, offB + threadIdx.x, f);
    }
    __syncthreads();
    int lane = threadIdx.x & 63;
    int quad = lane >> 4;
    int m = lane & 15;
    int w = threadIdx.x >> 6;
    int tile = blockIdx.x * 4 + w;
    size_t row = (size_t)tile * 16 + m;
    f4v acc[4];
    #pragma unroll
    for (int nt = 0; nt < 4; nt++) {
        float b = sB1[nt * 16 + m];
        acc[nt] = (f4v){b, b, b, b};
    }
    float av[8]; s8v ah, al;
    #pragma unroll
    for (int ks = 0; ks < 2; ks++) {
        ldrow8(A1, fa, row, ks, quad, av);
        make_afrag(av, ah, al);
        mfma3(s1h, s1l, ks, lane, ah, al, acc);
    }
    #pragma unroll
    for (int ks = 0; ks < 2; ks++) {
        ldrow8(aggr, 1, row, ks, quad, av);
        make_afrag(av, ah, al);
        mfma3(s1h, s1l, 2 + ks, lane, ah, al, acc);
    }
    #pragma unroll
    for (int r = 0; r < 4; r++)
        #pragma unroll
        for (int nt = 0; nt < 4; nt++)
            zbuf[w][(quad * 4 + r) * 68 + nt * 16 + m] = fmaxf(acc[nt][r], 0.f);
    f4v acc2[4];
    #pragma unroll
    for (int nt = 0; nt < 4; nt++) {
        float b = sB2[nt * 16 + m];
        acc2[nt] = (f4v){b, b, b, b};
    }
    #pragma unroll
    for (int ks = 0; ks < 2; ks++) {
        #pragma unroll
        for (int jx = 0; jx < 8; jx++)
            av[jx] = zbuf[w][m * 68 + ks * 32 + quad * 8 + jx];
        make_afrag(av, ah, al);
        mfma3(s2h, s2l, ks, lane, ah, al, acc2);
    }
    #pragma unroll
    for (int r = 0; r < 4; r++) {
        size_t rr = (size_t)(tile * 16 + quad * 4 + r) * 64 + m;
        #pragma unroll
        for (int nt = 0; nt < 4; nt++)
            NTS(&hout[rr + nt * 16], acc2[nt][r]);
    }
}

// ---------------------------------------------------------------- pool + head
__global__ __launch_bounds__(256) void k_poolhead(
    const float* __restrict__ h, const int* __restrict__ batch,
    const void* __restrict__ Wo1, const void* __restrict__ bo1,
    const void* __restrict__ Wo2, const void* __restrict__ bo2,
    const int* __restrict__ flag, void* __restrict__ out) {
    __shared__ float red[4][64];
    int b = blockIdx.x;
    int lo = 0, hi = N_NODES;
    while (lo < hi) { int mid = (lo + hi) >> 1; if (batch[mid] < b) lo = mid + 1; else hi = mid; }
    int start = lo;
    hi = N_NODES;
    while (lo < hi) { int mid = (lo + hi) >> 1; if (batch[mid] < b + 1) lo = mid + 1; else hi = mid; }
    int end = lo;
    int lane = threadIdx.x & 63;
    int w = threadIdx.x >> 6;
    float s = 0.f;
    for (int n = start + w; n < end; n += 4)
        s += h[(size_t)n * 64 + lane];
    red[w][lane] = s;
    __syncthreads();
    if (w == 0) {
        int f = *flag;
        float tot = red[0][lane] + red[1][lane] + red[2][lane] + red[3][lane];
        float c = (float)(end - start);
        float p = fmaxf(tot / fmaxf(c, 1.0f), 0.f);
        float acc = ldx(bo1, lane, f);
        #pragma unroll
        for (int kk = 0; kk < 64; kk++)
            acc += __shfl(p, kk) * ldx(Wo1, kk * 64 + lane, f);
        float t1 = fmaxf(acc, 0.f);
        float acc2 = (lane < OUT_DIM) ? ldx(bo2, lane, f) : 0.f;
        #pragma unroll
        for (int kk = 0; kk < 64; kk++) {
            float wv = (lane < OUT_DIM) ? ldx(Wo2, kk * OUT_DIM + lane, f) : 0.f;
            acc2 += __shfl(t1, kk) * wv;
        }
        if (lane < OUT_DIM) {
            if (f) ((float*)out)[b * OUT_DIM + lane] = acc2;
            else   ((bf16*)out)[b * OUT_DIM + lane] = __float2bfloat16(acc2);
        }
    }
}

extern "C" void kernel_launch(void* const* d_in, const int* in_sizes, int n_in,
                              void* d_out, int out_size, void* d_ws, size_t ws_size,
                              hipStream_t stream) {
    const int expect[19] = {
        N_NODES * 64, N_EDGES * 6, N_TRI * 6,
        L_LAYERS * 76 * 64, L_LAYERS * 64,
        L_LAYERS * 128 * 64, L_LAYERS * 64,
        L_LAYERS * 128 * 64, L_LAYERS * 64,
        L_LAYERS * 64 * 64, L_LAYERS * 64,
        64 * 64, 64, 64 * OUT_DIM, OUT_DIM,
        2 * N_EDGES, N_TRI, N_TRI, N_NODES
    };

    char* ws = (char*)d_ws;
    float* hA     = (float*)(ws + 0);
    float* agg_e  = (float*)(ws + 4096000);
    float* aggr   = (float*)(ws + 8192000);
    float* X      = (float*)(ws + 12288000);
    float* Y      = (float*)(ws + 16384000);
    int*   flag   = (int*)(ws + 20480000);
    int*   cur_t  = (int*)(ws + 20480256);
    int*   cur_e  = (int*)(ws + 20544256);
    int*   tri_o  = (int*)(ws + 20608256);
    int*   k_srt  = (int*)(ws + 23168256);
    int*   src_s  = (int*)(ws + 25728256);
    float* hB     = (float*)(ws + 26752256);
    const size_t FULL_NEED = 30848256u;

    const int out_n = N_B * OUT_DIM;

    int perm[19];
    bool used[64];
    for (int i = 0; i < 64; i++) used[i] = false;
    int fail_slot = -1;
    for (int i = 0; i < 19; i++) {
        perm[i] = -1;
        for (int jj = 0; jj < n_in && jj < 64; jj++) {
            if (!used[jj] && in_sizes[jj] == expect[i]) { used[jj] = true; perm[i] = jj; break; }
        }
        if (perm[i] < 0 && fail_slot < 0) fail_slot = i;
    }

    if (n_in < 19 || fail_slot >= 0 || ws_size < FULL_NEED) {
        float code = (ws_size < FULL_NEED) ? 40000.0f
                   : (n_in < 19)           ? 50000.0f
                   : 20000.0f + 1000.0f * (float)fail_slot;
        k_probe<<<1, 64, 0, stream>>>(d_in[0], (int*)d_ws);
        k_fill<<<(out_n + 255) / 256, 256, 0, stream>>>(d_out, (int*)d_ws, code, out_n);
        return;
    }

    const void* x    = d_in[perm[0]];
    const void* rbf  = d_in[perm[1]];
    const void* cbf  = d_in[perm[2]];
    const void* W1   = d_in[perm[3]];
    const void* b1   = d_in[perm[4]];
    const void* W2   = d_in[perm[5]];
    const void* b2   = d_in[perm[6]];
    const void* Wn1  = d_in[perm[7]];
    const void* bn1  = d_in[perm[8]];
    const void* Wn2  = d_in[perm[9]];
    const void* bn2  = d_in[perm[10]];
    const void* Wo1  = d_in[perm[11]];
    const void* bo1  = d_in[perm[12]];
    const void* Wo2  = d_in[perm[13]];
    const void* bo2  = d_in[perm[14]];
    const int* edge_index = (const int*)d_in[perm[15]];
    const int* k_idx = (const int*)d_in[perm[16]];
    const int* j_idx = (const int*)d_in[perm[17]];
    const int* batch = (const int*)d_in[perm[18]];

    const int TB = (N_TRI + 255) / 256;
    const int EB = (N_EDGES + 255) / 256;

    k_setup<<<64, 256, 0, stream>>>(rbf, flag, cur_t);
    k_hist2<<<TB + EB, 256, 0, stream>>>(j_idx, edge_index, cur_t, cur_e);
    k_scan2<<<2, 256, 0, stream>>>(cur_t, cur_e);
    k_scatter2<<<TB + EB, 256, 0, stream>>>(j_idx, k_idx, edge_index,
                                            cur_t, cur_e, tri_o, k_srt, src_s);

    // A/B measurement: run the deterministic 3-layer pipeline TWICE.
    // Second pass restarts from x and recomputes identical values.
    for (int pass = 0; pass < 2; pass++) {
        const void* hc = x;
        int hws = 0;
        float* hout = hA;
        for (int l = 0; l < L_LAYERS; l++) {
            size_t offW1l = (size_t)l * 76 * 64;
            size_t offW2l = (size_t)l * 128 * 64;
            size_t offWn2 = (size_t)l * 64 * 64;
            size_t offB   = (size_t)l * 64;
            k_lin2out<<<250, 256, 0, stream>>>(hc, hws, W1, offW1l, b1,
                                               W2, offW2l, b2, offB, flag, X, Y);
            k_tri_seg<<<4000, 256, 0, stream>>>(cur_t, tri_o, k_srt, X, rbf, cbf,
                                                W1, offW1l, flag, agg_e);
            k_lin1<<<250, 256, 0, stream>>>(agg_e, W2, offW2l + 64 * 64, flag, X);
            k_edge_s<<<4000, 256, 0, stream>>>(cur_e, src_s, Y, X, aggr);
            k_node_f<<<250, 256, 0, stream>>>(hc, hws, aggr, Wn1, bn1, Wn2, bn2,
                                              offW2l, offB, offWn2, flag, hout);
            hc = hout; hws = 1;
            hout = (hout == hA) ? hB : hA;
        }
    }
    k_poolhead<<<N_B, 256, 0, stream>>>(hA, batch, Wo1, bo1, Wo2, bo2, flag, d_out);
}

// Round 15
// 342.561 us; speedup vs baseline: 1.6836x; 1.6836x over previous
//
#include <hip/hip_runtime.h>
#include <hip/hip_bf16.h>

// DimeNet-like GNN, f32 in/out. Round 14: dispatch-count attack (round-13 A/B
// measured ~12.5us per dispatch, kernels only ~2-5us). Per layer 5 -> 2:
//  k_tri_seg (unchanged) + k_meg (fused: Ad MFMA from global-B frags, merged
//  4-bucket edge stream with aggr kept in LDS, nt-distributed node MLP, and
//  next layer's X/Y computed from the fresh h' tile). 21 -> 12 dispatches.

#define N_NODES 16000
#define N_EDGES 256000
#define N_TRI   640000
#define N_B     128
#define OUT_DIM 32
#define L_LAYERS 3

typedef __hip_bfloat16 bf16;
typedef short s8v __attribute__((ext_vector_type(8)));
typedef float f4v __attribute__((ext_vector_type(4)));

#define NTS(p, v) __builtin_nontemporal_store((v), (p))

__device__ __forceinline__ float ldx(const void* p, size_t i, int f) {
    if (f) return ((const float*)p)[i];
    return __bfloat162float(((const bf16*)p)[i]);
}

__device__ __forceinline__ unsigned short f2bf_rne(float x) {
    unsigned int u = __float_as_uint(x);
    unsigned int r = (u + 0x7FFFu + ((u >> 16) & 1u)) >> 16;
    return (unsigned short)r;
}
__device__ __forceinline__ float bf2f(unsigned short b) {
    return __uint_as_float(((unsigned int)b) << 16);
}
__device__ __forceinline__ void split2(float a, unsigned short& h, unsigned short& l) {
    h = f2bf_rne(a);
    l = f2bf_rne(a - bf2f(h));
}
__device__ __forceinline__ void make_afrag(const float* av, s8v& ah, s8v& al) {
    #pragma unroll
    for (int j = 0; j < 8; j++) {
        unsigned short h, l; split2(av[j], h, l);
        ah[j] = (short)h; al[j] = (short)l;
    }
}

// B-fragment loaded straight from global W (row-major KxN, N=64), split in regs.
__device__ __forceinline__ void ldbfrag(const void* W, size_t offW, int ks, int nt,
                                        int lane, int f, s8v& bh, s8v& bl) {
    int k0 = ks * 32 + ((lane >> 4) & 3) * 8;
    int n = nt * 16 + (lane & 15);
    float wv[8];
    #pragma unroll
    for (int j = 0; j < 8; j++)
        wv[j] = ldx(W, offW + (size_t)(k0 + j) * 64 + n, f);
    make_afrag(wv, bh, bl);
}

// one-tile 3-product split MFMA with global-loaded B
__device__ __forceinline__ void mfma1g(const void* W, size_t offW, int ks, int nt,
                                       int lane, int f, const s8v& ah, const s8v& al,
                                       f4v& acc) {
    s8v bh, bl;
    ldbfrag(W, offW, ks, nt, lane, f, bh, bl);
    acc = __builtin_amdgcn_mfma_f32_16x16x32_bf16(ah, bh, acc, 0, 0, 0);
    acc = __builtin_amdgcn_mfma_f32_16x16x32_bf16(al, bh, acc, 0, 0, 0);
    acc = __builtin_amdgcn_mfma_f32_16x16x32_bf16(ah, bl, acc, 0, 0, 0);
}

__device__ __forceinline__ void stageW(const void* W, size_t offW, int KS, int f,
                                       unsigned short* sBhi, unsigned short* sBlo) {
    for (int idx = threadIdx.x; idx < KS * 2048; idx += 256) {
        int jj = idx & 7, ln = (idx >> 3) & 63, nt = (idx >> 9) & 3, ks = idx >> 11;
        int k = ks * 32 + (ln >> 4) * 8 + jj;
        int n = nt * 16 + (ln & 15);
        float w = ldx(W, offW + (size_t)k * 64 + n, f);
        unsigned short h_, l_; split2(w, h_, l_);
        sBhi[idx] = h_; sBlo[idx] = l_;
    }
}

__device__ __forceinline__ void mfma3(const unsigned short* sBhi, const unsigned short* sBlo,
                                      int ks, int lane, const s8v& ah, const s8v& al,
                                      f4v acc[4]) {
    #pragma unroll
    for (int nt = 0; nt < 4; nt++) {
        s8v bh = *(const s8v*)&sBhi[(ks * 4 + nt) * 512 + lane * 8];
        s8v bl = *(const s8v*)&sBlo[(ks * 4 + nt) * 512 + lane * 8];
        acc[nt] = __builtin_amdgcn_mfma_f32_16x16x32_bf16(ah, bh, acc[nt], 0, 0, 0);
        acc[nt] = __builtin_amdgcn_mfma_f32_16x16x32_bf16(al, bh, acc[nt], 0, 0, 0);
        acc[nt] = __builtin_amdgcn_mfma_f32_16x16x32_bf16(ah, bl, acc[nt], 0, 0, 0);
    }
}

__device__ __forceinline__ void ldrow8(const void* A, int fa, size_t row, int ks,
                                       int quad, float av[8]) {
    if (fa) {
        const float* p = (const float*)A + row * 64 + ks * 32 + quad * 8;
        float4 x0 = ((const float4*)p)[0], x1 = ((const float4*)p)[1];
        av[0] = x0.x; av[1] = x0.y; av[2] = x0.z; av[3] = x0.w;
        av[4] = x1.x; av[5] = x1.y; av[6] = x1.z; av[7] = x1.w;
    } else {
        const bf16* p = (const bf16*)A + row * 64 + ks * 32 + quad * 8;
        #pragma unroll
        for (int j = 0; j < 8; j++) av[j] = __bfloat162float(p[j]);
    }
}

// ---------------------------------------------------------------- diag helpers
__global__ void k_probe(const void* __restrict__ rbf, int* __restrict__ flag) {
    if (threadIdx.x == 0 && blockIdx.x == 0) {
        const float* p = (const float*)rbf;
        int good = 0;
        for (int i = 0; i < 256; i++) {
            float v = fabsf(p[i]);
            if (v > 1e-4f && v < 100.0f) good++;
        }
        *flag = (good > 192) ? 1 : 0;
    }
}
__global__ void k_fill(void* __restrict__ out, const int* __restrict__ flag,
                       float val, int n) {
    int i = blockIdx.x * blockDim.x + threadIdx.x;
    if (i < n) {
        if (*flag) ((float*)out)[i] = val;
        else       ((bf16*)out)[i] = __float2bfloat16(val);
    }
}

// ---------------------------------------------------------------- setup
__global__ void k_setup(const void* __restrict__ rbf, int* __restrict__ flag,
                        int* __restrict__ cur) {
    int i = blockIdx.x * blockDim.x + threadIdx.x;
    int stride = gridDim.x * blockDim.x;
    for (; i < 2 * N_NODES; i += stride) cur[i] = 0;
    if (blockIdx.x == 0 && threadIdx.x < 64) {
        const float* p = (const float*)rbf;
        int good = 0;
        #pragma unroll
        for (int q = 0; q < 4; q++) {
            float v = fabsf(p[threadIdx.x * 4 + q]);
            if (v > 1e-4f && v < 100.0f) good++;
        }
        #pragma unroll
        for (int d = 1; d < 64; d <<= 1)
            good += __shfl_xor(good, d);
        if (threadIdx.x == 0) *flag = (good > 192) ? 1 : 0;
    }
}

__global__ void k_hist2(const int* __restrict__ j_idx, const int* __restrict__ edge_index,
                        int* __restrict__ cur_t, int* __restrict__ cur_e) {
    const int TB = (N_TRI + 255) / 256;
    if ((int)blockIdx.x < TB) {
        int i = blockIdx.x * 256 + threadIdx.x;
        if (i < N_TRI) {
            unsigned j = (unsigned)j_idx[i];
            if (j < N_NODES) atomicAdd(&cur_t[j], 1);
        }
    } else {
        int i = (blockIdx.x - TB) * 256 + threadIdx.x;
        if (i < N_EDGES) {
            unsigned d = (unsigned)edge_index[N_EDGES + i];
            if (d < N_NODES) atomicAdd(&cur_e[d], 1);
        }
    }
}

__global__ __launch_bounds__(256) void k_scan2(int* __restrict__ a, int* __restrict__ b) {
    int* cnt = (blockIdx.x == 0) ? a : b;
    __shared__ int part[256];
    int tid = threadIdx.x;
    const int PER = (N_NODES + 255) / 256;
    int base = tid * PER;
    int s = 0;
    for (int i = 0; i < PER; i++) {
        int idx = base + i;
        if (idx < N_NODES) s += cnt[idx];
    }
    part[tid] = s;
    __syncthreads();
    for (int d = 1; d < 256; d <<= 1) {
        int v = (tid >= d) ? part[tid - d] : 0;
        __syncthreads();
        part[tid] += v;
        __syncthreads();
    }
    int run = (tid > 0) ? part[tid - 1] : 0;
    for (int i = 0; i < PER; i++) {
        int idx = base + i;
        if (idx < N_NODES) {
            int v = cnt[idx];
            cnt[idx] = run;
            run += v;
        }
    }
}

__global__ void k_scatter2(const int* __restrict__ j_idx, const int* __restrict__ k_idx,
                           const int* __restrict__ edge_index,
                           int* __restrict__ cur_t, int* __restrict__ cur_e,
                           int* __restrict__ tri_o, int* __restrict__ k_srt,
                           int* __restrict__ src_s) {
    const int TB = (N_TRI + 255) / 256;
    if ((int)blockIdx.x < TB) {
        int i = blockIdx.x * 256 + threadIdx.x;
        if (i < N_TRI) {
            unsigned j = (unsigned)j_idx[i];
            if (j < N_NODES) {
                int pos = atomicAdd(&cur_t[j], 1);
                if ((unsigned)pos < (unsigned)N_TRI) {
                    unsigned k = (unsigned)k_idx[i]; if (k >= N_NODES) k = 0;
                    tri_o[pos] = i;
                    k_srt[pos] = (int)k;
                }
            }
        }
    } else {
        int e = (blockIdx.x - TB) * 256 + threadIdx.x;
        if (e < N_EDGES) {
            unsigned d = (unsigned)edge_index[N_EDGES + e];
            if (d < N_NODES) {
                int pos = atomicAdd(&cur_e[d], 1);
                if ((unsigned)pos < (unsigned)N_EDGES) {
                    unsigned s = (unsigned)edge_index[e]; if (s >= N_NODES) s = 0;
                    src_s[pos] = (int)s;
                }
            }
        }
    }
}

// ---------------------------------------------------------------- lin2out (layer 0 only)
__global__ __launch_bounds__(256) void k_lin2out(
    const void* __restrict__ A1, int a1ws,
    const void* __restrict__ W1, size_t offW1, const void* __restrict__ b1,
    const void* __restrict__ W2, size_t offW2, const void* __restrict__ b2,
    size_t offB, const int* __restrict__ flag,
    float* __restrict__ X, float* __restrict__ Y) {
    __shared__ unsigned short h1[2 * 2048], l1[2 * 2048];
    __shared__ unsigned short h2[2 * 2048], l2[2 * 2048];
    __shared__ float sB1[64], sB2[64];
    int f = *flag;
    int fa = a1ws ? 1 : f;
    stageW(W1, offW1, 2, f, h1, l1);
    stageW(W2, offW2, 2, f, h2, l2);
    if (threadIdx.x < 64) {
        sB1[threadIdx.x] = ldx(b1, offB + threadIdx.x, f);
        sB2[threadIdx.x] = ldx(b2, offB + threadIdx.x, f);
    }
    __syncthreads();
    int lane = threadIdx.x & 63;
    int quad = lane >> 4;
    int m = lane & 15;
    int tile = blockIdx.x * 4 + (threadIdx.x >> 6);
    size_t row = (size_t)tile * 16 + m;
    f4v accH[4], accS[4];
    #pragma unroll
    for (int nt = 0; nt < 4; nt++) {
        float bh = sB1[nt * 16 + m], bs = sB2[nt * 16 + m];
        accH[nt] = (f4v){bh, bh, bh, bh};
        accS[nt] = (f4v){bs, bs, bs, bs};
    }
    float av[8]; s8v ah, al;
    #pragma unroll
    for (int ks = 0; ks < 2; ks++) {
        ldrow8(A1, fa, row, ks, quad, av);
        make_afrag(av, ah, al);
        mfma3(h1, l1, ks, lane, ah, al, accH);
        mfma3(h2, l2, ks, lane, ah, al, accS);
    }
    #pragma unroll
    for (int r = 0; r < 4; r++) {
        size_t rr = (size_t)(tile * 16 + quad * 4 + r) * 64 + m;
        #pragma unroll
        for (int nt = 0; nt < 4; nt++) {
            NTS(&X[rr + nt * 16], accH[nt][r]);
            NTS(&Y[rr + nt * 16], accS[nt][r]);
        }
    }
}

// ---------------------------------------------------------------- tri segment sum
__global__ __launch_bounds__(256) void k_tri_seg(
    const int* __restrict__ ends, const int* __restrict__ tri_o,
    const int* __restrict__ k_srt, const float* __restrict__ Hh,
    const void* __restrict__ rbf, const void* __restrict__ cbf,
    const void* __restrict__ W1, size_t offW,
    const int* __restrict__ flag, float* __restrict__ agg_e) {
    int f = *flag;
    int c = threadIdx.x & 63;
    float wr[6], wc[6];
    #pragma unroll
    for (int q = 0; q < 6; q++) {
        wr[q] = ldx(W1, offW + (size_t)(64 + q) * 64 + c, f);
        wc[q] = ldx(W1, offW + (size_t)(70 + q) * 64 + c, f);
    }
    int j = blockIdx.x * 4 + (threadIdx.x >> 6);
    int p0 = (j == 0) ? 0 : ends[j - 1];
    int p1 = ends[j];
    if (p0 < 0) p0 = 0; if (p0 > N_TRI) p0 = N_TRI;
    if (p1 < p0) p1 = p0; if (p1 > N_TRI) p1 = N_TRI;
    float rb = 0.f;
    #pragma unroll
    for (int q = 0; q < 6; q++)
        rb += ldx(rbf, (size_t)j * 6 + q, f) * wr[q];
    float s = 0.f;
    for (int p = p0; p < p1; p += 4) {
        int tq[4], kq[4];
        float hv[4], cb[4][6];
        #pragma unroll
        for (int i = 0; i < 4; i++) {
            int ok = (p + i < p1);
            int t = ok ? tri_o[p + i] : -1;
            if ((unsigned)t >= N_TRI) t = -1;
            tq[i] = t;
            int k = ok ? k_srt[p + i] : 0;
            if ((unsigned)k >= N_NODES) k = 0;
            kq[i] = k;
        }
        #pragma unroll
        for (int i = 0; i < 4; i++)
            hv[i] = Hh[(size_t)kq[i] * 64 + c];
        #pragma unroll
        for (int i = 0; i < 4; i++) {
            if (tq[i] >= 0) {
                if (f) {
                    const float2* cp = (const float2*)((const float*)cbf + (size_t)tq[i] * 6);
                    float2 c0 = cp[0], c1 = cp[1], c2 = cp[2];
                    cb[i][0] = c0.x; cb[i][1] = c0.y; cb[i][2] = c1.x;
                    cb[i][3] = c1.y; cb[i][4] = c2.x; cb[i][5] = c2.y;
                } else {
                    #pragma unroll
                    for (int q = 0; q < 6; q++)
                        cb[i][q] = ldx(cbf, (size_t)tq[i] * 6 + q, 0);
                }
            }
        }
        #pragma unroll
        for (int i = 0; i < 4; i++) {
            if (tq[i] < 0) continue;
            float v = hv[i] + rb;
            #pragma unroll
            for (int q = 0; q < 6; q++)
                v += cb[i][q] * wc[q];
            s += fmaxf(v, 0.f);
        }
    }
    NTS(&agg_e[(size_t)j * 64 + c], s);
}

// ---------------------------------------------------------------- k_meg: Ad + edge + node + next X/Y
// grid 1000, block = 16-node tile [16b, 16b+16). wave w owns nt=w for MFMAs and
// nodes 16b+4w..16b+4w+3 for edge buckets (contiguous in sorted order).
__global__ __launch_bounds__(256) void k_meg(
    const int* __restrict__ ends_e, const int* __restrict__ src_s,
    const float* __restrict__ Hs, const float* __restrict__ agg_e,
    const void* __restrict__ A1, int a1ws,
    const void* __restrict__ W2, size_t offW2a,
    const void* __restrict__ Wn1, const void* __restrict__ bn1,
    const void* __restrict__ Wn2, const void* __restrict__ bn2,
    size_t offWn1, size_t offB, size_t offWn2,
    const void* __restrict__ W1n, const void* __restrict__ b1n,
    const void* __restrict__ W2n, const void* __restrict__ b2n,
    size_t offW1n, size_t offW2n, size_t offBn, int has_next,
    const int* __restrict__ flag,
    float* __restrict__ hout, float* __restrict__ Xn, float* __restrict__ Yn) {
    __shared__ float sAd[16 * 68];
    __shared__ float sAg[16 * 68];
    __shared__ float sT[16 * 68];
    int f = *flag;
    int fa = a1ws ? 1 : f;
    int lane = threadIdx.x & 63;
    int w = threadIdx.x >> 6;
    int quad = lane >> 4;
    int m = lane & 15;
    int bb = blockIdx.x;
    size_t row = (size_t)bb * 16 + m;

    // ---- Phase A: Ad tile (agg_e rows @ W2a), wave w computes nt=w slice ----
    {
        f4v acc = (f4v){0.f, 0.f, 0.f, 0.f};
        float av[8]; s8v ah, al;
        #pragma unroll
        for (int ks = 0; ks < 2; ks++) {
            const float* p = agg_e + row * 64 + ks * 32 + quad * 8;
            float4 x0 = ((const float4*)p)[0], x1 = ((const float4*)p)[1];
            av[0] = x0.x; av[1] = x0.y; av[2] = x0.z; av[3] = x0.w;
            av[4] = x1.x; av[5] = x1.y; av[6] = x1.z; av[7] = x1.w;
            make_afrag(av, ah, al);
            mfma1g(W2, offW2a, ks, w, lane, f, ah, al, acc);
        }
        #pragma unroll
        for (int r = 0; r < 4; r++)
            sAd[(quad * 4 + r) * 68 + w * 16 + m] = acc[r];
    }
    __syncthreads();

    // ---- Phase B: merged 4-bucket edge stream, aggr -> sAg ----
    {
        int dbase = bb * 16 + w * 4;
        int q0 = (dbase == 0) ? 0 : ends_e[dbase - 1];
        int e1 = ends_e[dbase], e2 = ends_e[dbase + 1];
        int e3 = ends_e[dbase + 2], q1 = ends_e[dbase + 3];
        if (q0 < 0) q0 = 0; if (q0 > N_EDGES) q0 = N_EDGES;
        if (q1 < q0) q1 = q0; if (q1 > N_EDGES) q1 = N_EDGES;
        if (e1 < q0) e1 = q0; if (e1 > q1) e1 = q1;
        if (e2 < e1) e2 = e1; if (e2 > q1) e2 = q1;
        if (e3 < e2) e3 = e2; if (e3 > q1) e3 = q1;
        float ad0 = sAd[(w * 4 + 0) * 68 + lane];
        float ad1 = sAd[(w * 4 + 1) * 68 + lane];
        float ad2 = sAd[(w * 4 + 2) * 68 + lane];
        float ad3 = sAd[(w * 4 + 3) * 68 + lane];
        float s0 = 0.f, s1 = 0.f, s2 = 0.f, s3 = 0.f;
        for (int p = q0; p < q1; p += 8) {
            int ss[8]; float hv[8];
            #pragma unroll
            for (int i = 0; i < 8; i++) {
                int sv = (p + i < q1) ? src_s[p + i] : 0;
                if ((unsigned)sv >= N_NODES) sv = 0;
                ss[i] = sv;
            }
            #pragma unroll
            for (int i = 0; i < 8; i++)
                hv[i] = Hs[(size_t)ss[i] * 64 + lane];
            #pragma unroll
            for (int i = 0; i < 8; i++) {
                int pp = p + i;
                if (pp >= q1) continue;
                float ad = (pp >= e3) ? ad3 : (pp >= e2) ? ad2 : (pp >= e1) ? ad1 : ad0;
                float v = fmaxf(hv[i] + ad, 0.f);
                if (pp < e1) s0 += v;
                else if (pp < e2) s1 += v;
                else if (pp < e3) s2 += v;
                else s3 += v;
            }
        }
        sAg[(w * 4 + 0) * 68 + lane] = s0;
        sAg[(w * 4 + 1) * 68 + lane] = s1;
        sAg[(w * 4 + 2) * 68 + lane] = s2;
        sAg[(w * 4 + 3) * 68 + lane] = s3;
    }
    __syncthreads();

    // ---- Phase C: node MLP, nt=w slice per wave ----
    float av[8]; s8v ah, al;
    f4v acc1;
    {
        float b = ldx(bn1, offB + w * 16 + m, f);
        acc1 = (f4v){b, b, b, b};
        #pragma unroll
        for (int ks = 0; ks < 2; ks++) {
            ldrow8(A1, fa, row, ks, quad, av);
            make_afrag(av, ah, al);
            mfma1g(Wn1, offWn1, ks, w, lane, f, ah, al, acc1);
        }
        #pragma unroll
        for (int ks = 0; ks < 2; ks++) {
            #pragma unroll
            for (int j = 0; j < 8; j++)
                av[j] = sAg[m * 68 + ks * 32 + quad * 8 + j];
            make_afrag(av, ah, al);
            mfma1g(Wn1, offWn1 + 64 * 64, ks, w, lane, f, ah, al, acc1);
        }
        #pragma unroll
        for (int r = 0; r < 4; r++)
            sT[(quad * 4 + r) * 68 + w * 16 + m] = fmaxf(acc1[r], 0.f);
    }
    __syncthreads();
    f4v acc2;
    {
        float b = ldx(bn2, offB + w * 16 + m, f);
        acc2 = (f4v){b, b, b, b};
        #pragma unroll
        for (int ks = 0; ks < 2; ks++) {
            #pragma unroll
            for (int j = 0; j < 8; j++)
                av[j] = sT[m * 68 + ks * 32 + quad * 8 + j];
            make_afrag(av, ah, al);
            mfma1g(Wn2, offWn2, ks, w, lane, f, ah, al, acc2);
        }
        #pragma unroll
        for (int r = 0; r < 4; r++)
            NTS(&hout[(size_t)(bb * 16 + quad * 4 + r) * 64 + w * 16 + m], acc2[r]);
    }
    if (has_next) {
        // h' tile -> sAg (reuse) for A-frags of next-layer X/Y
        #pragma unroll
        for (int r = 0; r < 4; r++)
            sAg[(quad * 4 + r) * 68 + w * 16 + m] = acc2[r];
        __syncthreads();
        float bx = ldx(b1n, offBn + w * 16 + m, f);
        float by = ldx(b2n, offBn + w * 16 + m, f);
        f4v aX = (f4v){bx, bx, bx, bx};
        f4v aY = (f4v){by, by, by, by};
        #pragma unroll
        for (int ks = 0; ks < 2; ks++) {
            #pragma unroll
            for (int j = 0; j < 8; j++)
                av[j] = sAg[m * 68 + ks * 32 + quad * 8 + j];
            make_afrag(av, ah, al);
            mfma1g(W1n, offW1n, ks, w, lane, f, ah, al, aX);
            mfma1g(W2n, offW2n, ks, w, lane, f, ah, al, aY);
        }
        #pragma unroll
        for (int r = 0; r < 4; r++) {
            size_t rr = (size_t)(bb * 16 + quad * 4 + r) * 64 + w * 16 + m;
            NTS(&Xn[rr], aX[r]);
            NTS(&Yn[rr], aY[r]);
        }
    }
}

// ---------------------------------------------------------------- pool + head
__global__ __launch_bounds__(256) void k_poolhead(
    const float* __restrict__ h, const int* __restrict__ batch,
    const void* __restrict__ Wo1, const void* __restrict__ bo1,
    const void* __restrict__ Wo2, const void* __restrict__ bo2,
    const int* __restrict__ flag, void* __restrict__ out) {
    __shared__ float red[4][64];
    int b = blockIdx.x;
    int lo = 0, hi = N_NODES;
    while (lo < hi) { int mid = (lo + hi) >> 1; if (batch[mid] < b) lo = mid + 1; else hi = mid; }
    int start = lo;
    hi = N_NODES;
    while (lo < hi) { int mid = (lo + hi) >> 1; if (batch[mid] < b + 1) lo = mid + 1; else hi = mid; }
    int end = lo;
    int lane = threadIdx.x & 63;
    int w = threadIdx.x >> 6;
    float s = 0.f;
    for (int n = start + w; n < end; n += 4)
        s += h[(size_t)n * 64 + lane];
    red[w][lane] = s;
    __syncthreads();
    if (w == 0) {
        int f = *flag;
        float tot = red[0][lane] + red[1][lane] + red[2][lane] + red[3][lane];
        float c = (float)(end - start);
        float p = fmaxf(tot / fmaxf(c, 1.0f), 0.f);
        float acc = ldx(bo1, lane, f);
        #pragma unroll
        for (int kk = 0; kk < 64; kk++)
            acc += __shfl(p, kk) * ldx(Wo1, kk * 64 + lane, f);
        float t1 = fmaxf(acc, 0.f);
        float acc2 = (lane < OUT_DIM) ? ldx(bo2, lane, f) : 0.f;
        #pragma unroll
        for (int kk = 0; kk < 64; kk++) {
            float wv = (lane < OUT_DIM) ? ldx(Wo2, kk * OUT_DIM + lane, f) : 0.f;
            acc2 += __shfl(t1, kk) * wv;
        }
        if (lane < OUT_DIM) {
            if (f) ((float*)out)[b * OUT_DIM + lane] = acc2;
            else   ((bf16*)out)[b * OUT_DIM + lane] = __float2bfloat16(acc2);
        }
    }
}

extern "C" void kernel_launch(void* const* d_in, const int* in_sizes, int n_in,
                              void* d_out, int out_size, void* d_ws, size_t ws_size,
                              hipStream_t stream) {
    const int expect[19] = {
        N_NODES * 64, N_EDGES * 6, N_TRI * 6,
        L_LAYERS * 76 * 64, L_LAYERS * 64,
        L_LAYERS * 128 * 64, L_LAYERS * 64,
        L_LAYERS * 128 * 64, L_LAYERS * 64,
        L_LAYERS * 64 * 64, L_LAYERS * 64,
        64 * 64, 64, 64 * OUT_DIM, OUT_DIM,
        2 * N_EDGES, N_TRI, N_TRI, N_NODES
    };

    char* ws = (char*)d_ws;
    float* hA     = (float*)(ws + 0);
    float* agg_e  = (float*)(ws + 4096000);
    float* aggr   = (float*)(ws + 8192000);   // unused (aggr now LDS-only)
    float* X      = (float*)(ws + 12288000);
    float* Y      = (float*)(ws + 16384000);
    int*   flag   = (int*)(ws + 20480000);
    int*   cur_t  = (int*)(ws + 20480256);
    int*   cur_e  = (int*)(ws + 20544256);
    int*   tri_o  = (int*)(ws + 20608256);
    int*   k_srt  = (int*)(ws + 23168256);
    int*   src_s  = (int*)(ws + 25728256);
    float* hB     = (float*)(ws + 26752256);
    const size_t FULL_NEED = 30848256u;
    (void)aggr;

    const int out_n = N_B * OUT_DIM;

    int perm[19];
    bool used[64];
    for (int i = 0; i < 64; i++) used[i] = false;
    int fail_slot = -1;
    for (int i = 0; i < 19; i++) {
        perm[i] = -1;
        for (int jj = 0; jj < n_in && jj < 64; jj++) {
            if (!used[jj] && in_sizes[jj] == expect[i]) { used[jj] = true; perm[i] = jj; break; }
        }
        if (perm[i] < 0 && fail_slot < 0) fail_slot = i;
    }

    if (n_in < 19 || fail_slot >= 0 || ws_size < FULL_NEED) {
        float code = (ws_size < FULL_NEED) ? 40000.0f
                   : (n_in < 19)           ? 50000.0f
                   : 20000.0f + 1000.0f * (float)fail_slot;
        k_probe<<<1, 64, 0, stream>>>(d_in[0], (int*)d_ws);
        k_fill<<<(out_n + 255) / 256, 256, 0, stream>>>(d_out, (int*)d_ws, code, out_n);
        return;
    }

    const void* x    = d_in[perm[0]];
    const void* rbf  = d_in[perm[1]];
    const void* cbf  = d_in[perm[2]];
    const void* W1   = d_in[perm[3]];
    const void* b1   = d_in[perm[4]];
    const void* W2   = d_in[perm[5]];
    const void* b2   = d_in[perm[6]];
    const void* Wn1  = d_in[perm[7]];
    const void* bn1  = d_in[perm[8]];
    const void* Wn2  = d_in[perm[9]];
    const void* bn2  = d_in[perm[10]];
    const void* Wo1  = d_in[perm[11]];
    const void* bo1  = d_in[perm[12]];
    const void* Wo2  = d_in[perm[13]];
    const void* bo2  = d_in[perm[14]];
    const int* edge_index = (const int*)d_in[perm[15]];
    const int* k_idx = (const int*)d_in[perm[16]];
    const int* j_idx = (const int*)d_in[perm[17]];
    const int* batch = (const int*)d_in[perm[18]];

    const int TB = (N_TRI + 255) / 256;
    const int EB = (N_EDGES + 255) / 256;

    k_setup<<<64, 256, 0, stream>>>(rbf, flag, cur_t);
    k_hist2<<<TB + EB, 256, 0, stream>>>(j_idx, edge_index, cur_t, cur_e);
    k_scan2<<<2, 256, 0, stream>>>(cur_t, cur_e);
    k_scatter2<<<TB + EB, 256, 0, stream>>>(j_idx, k_idx, edge_index,
                                            cur_t, cur_e, tri_o, k_srt, src_s);

    // layer 0's X/Y from dedicated GEMM; layers 1-2 get X/Y from k_meg
    k_lin2out<<<250, 256, 0, stream>>>(x, 0, W1, 0, b1, W2, 0, b2, 0, flag, X, Y);

    const void* hc = x;
    int hws = 0;
    float* hout = hA;
    for (int l = 0; l < L_LAYERS; l++) {
        size_t offW1l = (size_t)l * 76 * 64;
        size_t offW2l = (size_t)l * 128 * 64;
        size_t offWn2 = (size_t)l * 64 * 64;
        size_t offB   = (size_t)l * 64;
        size_t offW1n = (size_t)(l + 1) * 76 * 64;
        size_t offW2n = (size_t)(l + 1) * 128 * 64;
        size_t offBn  = (size_t)(l + 1) * 64;
        int has_next = (l < L_LAYERS - 1) ? 1 : 0;
        // agg_e = segsum_j relu(Hh[k] + rbf[j]@W1r + cbf[t]@W1c)
        k_tri_seg<<<4000, 256, 0, stream>>>(cur_t, tri_o, k_srt, X, rbf, cbf,
                                            W1, offW1l, flag, agg_e);
        // fused: Ad MFMA + edge buckets + node MLP + next-layer X/Y
        k_meg<<<1000, 256, 0, stream>>>(cur_e, src_s, Y, agg_e,
                                        hc, hws,
                                        W2, offW2l + 64 * 64,
                                        Wn1, bn1, Wn2, bn2,
                                        offW2l, offB, offWn2,
                                        W1, b1, W2, b2,
                                        offW1n, offW2n, offBn, has_next,
                                        flag, hout, X, Y);
        hc = hout; hws = 1;
        hout = (hout == hA) ? hB : hA;
    }
    k_poolhead<<<N_B, 256, 0, stream>>>(hA, batch, Wo1, bo1, Wo2, bo2, flag, d_out);
}

// Round 18
// 314.151 us; speedup vs baseline: 1.8359x; 1.0904x over previous
//
#include <hip/hip_runtime.h>
#include <hip/hip_bf16.h>

// DimeNet-like GNN, f32 in/out. Round 17: BUG FIX of r15/16's shared defect:
// the rewritten k_lin2out used one-wave-per-tile with the nt=w column trick,
// leaving 3/4 of X0/Y0 unwritten (valid only when all 4 waves share a tile,
// as in k_meg). Fixed: block-per-tile (grid 1000), wave w -> nt=w slice.
// Everything else identical to r16: 9 dispatches, k_meg fuses
// tri+Ad+edge+node+nextXY with all intermediates in LDS, X/Y double-buffered.

#define N_NODES 16000
#define N_EDGES 256000
#define N_TRI   640000
#define N_B     128
#define OUT_DIM 32
#define L_LAYERS 3

typedef __hip_bfloat16 bf16;
typedef short s8v __attribute__((ext_vector_type(8)));
typedef float f4v __attribute__((ext_vector_type(4)));

#define NTS(p, v) __builtin_nontemporal_store((v), (p))

__device__ __forceinline__ unsigned short f2bf_rne(float x) {
    unsigned int u = __float_as_uint(x);
    unsigned int r = (u + 0x7FFFu + ((u >> 16) & 1u)) >> 16;
    return (unsigned short)r;
}
__device__ __forceinline__ float bf2f(unsigned short b) {
    return __uint_as_float(((unsigned int)b) << 16);
}
__device__ __forceinline__ void split2(float a, unsigned short& h, unsigned short& l) {
    h = f2bf_rne(a);
    l = f2bf_rne(a - bf2f(h));
}
__device__ __forceinline__ void make_afrag(const float* av, s8v& ah, s8v& al) {
    #pragma unroll
    for (int j = 0; j < 8; j++) {
        unsigned short h, l; split2(av[j], h, l);
        ah[j] = (short)h; al[j] = (short)l;
    }
}

// B-fragment straight from global W (row-major Kx64), split in regs.
__device__ __forceinline__ void ldbfrag(const float* W, int ks, int nt,
                                        int lane, s8v& bh, s8v& bl) {
    int k0 = ks * 32 + ((lane >> 4) & 3) * 8;
    int n = nt * 16 + (lane & 15);
    float wv[8];
    #pragma unroll
    for (int j = 0; j < 8; j++)
        wv[j] = W[(size_t)(k0 + j) * 64 + n];
    make_afrag(wv, bh, bl);
}

__device__ __forceinline__ void mfma1g(const float* W, int ks, int nt, int lane,
                                       const s8v& ah, const s8v& al, f4v& acc) {
    s8v bh, bl;
    ldbfrag(W, ks, nt, lane, bh, bl);
    acc = __builtin_amdgcn_mfma_f32_16x16x32_bf16(ah, bh, acc, 0, 0, 0);
    acc = __builtin_amdgcn_mfma_f32_16x16x32_bf16(al, bh, acc, 0, 0, 0);
    acc = __builtin_amdgcn_mfma_f32_16x16x32_bf16(ah, bl, acc, 0, 0, 0);
}

__device__ __forceinline__ void ldrow8f(const float* A, size_t row, int ks,
                                        int quad, float av[8]) {
    const float* p = A + row * 64 + ks * 32 + quad * 8;
    float4 x0 = ((const float4*)p)[0], x1 = ((const float4*)p)[1];
    av[0] = x0.x; av[1] = x0.y; av[2] = x0.z; av[3] = x0.w;
    av[4] = x1.x; av[5] = x1.y; av[6] = x1.z; av[7] = x1.w;
}

// ---------------------------------------------------------------- diag helper
__global__ void k_fill(float* __restrict__ out, float val, int n) {
    int i = blockIdx.x * blockDim.x + threadIdx.x;
    if (i < n) out[i] = val;
}

// ---------------------------------------------------------------- setup
__global__ void k_setup(int* __restrict__ cur) {
    int i = blockIdx.x * blockDim.x + threadIdx.x;
    int stride = gridDim.x * blockDim.x;
    for (; i < 2 * N_NODES; i += stride) cur[i] = 0;
}

__global__ void k_hist2(const int* __restrict__ j_idx, const int* __restrict__ edge_index,
                        int* __restrict__ cur_t, int* __restrict__ cur_e) {
    const int TB = (N_TRI + 255) / 256;
    if ((int)blockIdx.x < TB) {
        int i = blockIdx.x * 256 + threadIdx.x;
        if (i < N_TRI) {
            unsigned j = (unsigned)j_idx[i];
            if (j < N_NODES) atomicAdd(&cur_t[j], 1);
        }
    } else {
        int i = (blockIdx.x - TB) * 256 + threadIdx.x;
        if (i < N_EDGES) {
            unsigned d = (unsigned)edge_index[N_EDGES + i];
            if (d < N_NODES) atomicAdd(&cur_e[d], 1);
        }
    }
}

__global__ __launch_bounds__(256) void k_scan2(int* __restrict__ a, int* __restrict__ b) {
    int* cnt = (blockIdx.x == 0) ? a : b;
    __shared__ int part[256];
    int tid = threadIdx.x;
    const int PER = (N_NODES + 255) / 256;
    int base = tid * PER;
    int s = 0;
    for (int i = 0; i < PER; i++) {
        int idx = base + i;
        if (idx < N_NODES) s += cnt[idx];
    }
    part[tid] = s;
    __syncthreads();
    for (int d = 1; d < 256; d <<= 1) {
        int v = (tid >= d) ? part[tid - d] : 0;
        __syncthreads();
        part[tid] += v;
        __syncthreads();
    }
    int run = (tid > 0) ? part[tid - 1] : 0;
    for (int i = 0; i < PER; i++) {
        int idx = base + i;
        if (idx < N_NODES) {
            int v = cnt[idx];
            cnt[idx] = run;
            run += v;
        }
    }
}

__global__ void k_scatter2(const int* __restrict__ j_idx, const int* __restrict__ k_idx,
                           const int* __restrict__ edge_index,
                           int* __restrict__ cur_t, int* __restrict__ cur_e,
                           int* __restrict__ tri_o, int* __restrict__ k_srt,
                           int* __restrict__ src_s) {
    const int TB = (N_TRI + 255) / 256;
    if ((int)blockIdx.x < TB) {
        int i = blockIdx.x * 256 + threadIdx.x;
        if (i < N_TRI) {
            unsigned j = (unsigned)j_idx[i];
            if (j < N_NODES) {
                int pos = atomicAdd(&cur_t[j], 1);
                if ((unsigned)pos < (unsigned)N_TRI) {
                    unsigned k = (unsigned)k_idx[i]; if (k >= N_NODES) k = 0;
                    tri_o[pos] = i;
                    k_srt[pos] = (int)k;
                }
            }
        }
    } else {
        int e = (blockIdx.x - TB) * 256 + threadIdx.x;
        if (e < N_EDGES) {
            unsigned d = (unsigned)edge_index[N_EDGES + e];
            if (d < N_NODES) {
                int pos = atomicAdd(&cur_e[d], 1);
                if ((unsigned)pos < (unsigned)N_EDGES) {
                    unsigned s = (unsigned)edge_index[e]; if (s >= N_NODES) s = 0;
                    src_s[pos] = (int)s;
                }
            }
        }
    }
    // cursors now hold bucket END offsets
}

// ---------------------------------------------------------------- lin2out (layer 0)
// FIXED: block per tile (grid 1000); all 4 waves share tile blockIdx.x,
// wave w computes column slice nt=w. X = x@W1h+b1, Y = x@W2h+b2.
__global__ __launch_bounds__(256) void k_lin2out(
    const float* __restrict__ x,
    const float* __restrict__ W1, const float* __restrict__ b1,
    const float* __restrict__ W2, const float* __restrict__ b2,
    float* __restrict__ X, float* __restrict__ Y) {
    int lane = threadIdx.x & 63;
    int w = threadIdx.x >> 6;
    int quad = lane >> 4;
    int m = lane & 15;
    int tile = blockIdx.x;
    size_t row = (size_t)tile * 16 + m;
    float bx = b1[w * 16 + m];
    float by = b2[w * 16 + m];
    f4v aX = (f4v){bx, bx, bx, bx};
    f4v aY = (f4v){by, by, by, by};
    float av[8]; s8v ah, al;
    #pragma unroll
    for (int ks = 0; ks < 2; ks++) {
        ldrow8f(x, row, ks, quad, av);
        make_afrag(av, ah, al);
        mfma1g(W1, ks, w, lane, ah, al, aX);
        mfma1g(W2, ks, w, lane, ah, al, aY);
    }
    #pragma unroll
    for (int r = 0; r < 4; r++) {
        size_t rr = (size_t)(tile * 16 + quad * 4 + r) * 64 + w * 16 + m;
        NTS(&X[rr], aX[r]);
        NTS(&Y[rr], aY[r]);
    }
}

// ---------------------------------------------------------------- k_meg
// Block bb owns nodes [16bb, 16bb+16). Phases (all LDS-chained):
//  T: tri buckets -> sA (agg rows)      A: Ad = sA @ W2a -> sB
//  B: edge buckets (+sB) -> sA (aggr)   C1: z = relu([h|aggr]@Wn1+bn1) -> sB
//  C2: h' = z@Wn2+bn2 -> global (+sA)   XY: next X/Y from h' tile
struct MegA {
    const int *ends_t, *tri_o, *k_srt, *ends_e, *src_s;
    const float *X, *Y;          // current Hh, Hs
    const float *rbf, *cbf, *A1; // A1 = h (or x) rows
    const float *W1l, *W2a, *Wn1l, *bn1l, *Wn2l, *bn2l;
    const float *W1n, *b1n, *W2n, *b2n;  // next-layer (valid if has_next)
    float *hout, *Xn, *Yn;
    int has_next;
};

__global__ __launch_bounds__(256) void k_meg(MegA g) {
    __shared__ float sA[16 * 68];
    __shared__ float sB[16 * 68];
    const int lane = threadIdx.x & 63;
    const int w = threadIdx.x >> 6;
    const int quad = lane >> 4;
    const int m = lane & 15;
    const int bb = blockIdx.x;
    const size_t row = (size_t)bb * 16 + m;
    float av[8]; s8v ah, al;

    // ---- Phase T: tri buckets (4 per wave, merged stream) -> sA ----
    {
        int nb = bb * 16 + w * 4;
        int q0 = (nb == 0) ? 0 : g.ends_t[nb - 1];
        int e1 = g.ends_t[nb], e2 = g.ends_t[nb + 1];
        int e3 = g.ends_t[nb + 2], q1 = g.ends_t[nb + 3];
        if (q0 < 0) q0 = 0; if (q0 > N_TRI) q0 = N_TRI;
        if (q1 < q0) q1 = q0; if (q1 > N_TRI) q1 = N_TRI;
        if (e1 < q0) e1 = q0; if (e1 > q1) e1 = q1;
        if (e2 < e1) e2 = e1; if (e2 > q1) e2 = q1;
        if (e3 < e2) e3 = e2; if (e3 > q1) e3 = q1;
        float wr[6], wc[6];
        #pragma unroll
        for (int q = 0; q < 6; q++) {
            wr[q] = g.W1l[(size_t)(64 + q) * 64 + lane];
            wc[q] = g.W1l[(size_t)(70 + q) * 64 + lane];
        }
        float rb[4];
        #pragma unroll
        for (int i = 0; i < 4; i++) {
            float r = 0.f;
            #pragma unroll
            for (int q = 0; q < 6; q++)
                r += g.rbf[(size_t)(nb + i) * 6 + q] * wr[q];
            rb[i] = r;
        }
        float s0 = 0.f, s1 = 0.f, s2 = 0.f, s3 = 0.f;
        for (int p = q0; p < q1; p += 4) {
            int tq[4], kq[4];
            float hv[4], cb[4][6];
            #pragma unroll
            for (int i = 0; i < 4; i++) {
                int ok = (p + i < q1);
                int t = ok ? g.tri_o[p + i] : -1;
                if ((unsigned)t >= N_TRI) t = -1;
                tq[i] = t;
                int k = ok ? g.k_srt[p + i] : 0;
                if ((unsigned)k >= N_NODES) k = 0;
                kq[i] = k;
            }
            #pragma unroll
            for (int i = 0; i < 4; i++)
                hv[i] = g.X[(size_t)kq[i] * 64 + lane];
            #pragma unroll
            for (int i = 0; i < 4; i++) {
                if (tq[i] >= 0) {
                    const float2* cp = (const float2*)(g.cbf + (size_t)tq[i] * 6);
                    float2 c0 = cp[0], c1 = cp[1], c2 = cp[2];
                    cb[i][0] = c0.x; cb[i][1] = c0.y; cb[i][2] = c1.x;
                    cb[i][3] = c1.y; cb[i][4] = c2.x; cb[i][5] = c2.y;
                }
            }
            #pragma unroll
            for (int i = 0; i < 4; i++) {
                int pp = p + i;
                if (tq[i] < 0) continue;
                float rbv = (pp >= e3) ? rb[3] : (pp >= e2) ? rb[2] : (pp >= e1) ? rb[1] : rb[0];
                float v = hv[i] + rbv;
                #pragma unroll
                for (int q = 0; q < 6; q++)
                    v += cb[i][q] * wc[q];
                v = fmaxf(v, 0.f);
                if (pp < e1) s0 += v;
                else if (pp < e2) s1 += v;
                else if (pp < e3) s2 += v;
                else s3 += v;
            }
        }
        sA[(w * 4 + 0) * 68 + lane] = s0;
        sA[(w * 4 + 1) * 68 + lane] = s1;
        sA[(w * 4 + 2) * 68 + lane] = s2;
        sA[(w * 4 + 3) * 68 + lane] = s3;
    }
    __syncthreads();

    // ---- Phase A: Ad = sA @ W2a, wave w -> nt=w slice -> sB ----
    {
        f4v acc = (f4v){0.f, 0.f, 0.f, 0.f};
        #pragma unroll
        for (int ks = 0; ks < 2; ks++) {
            #pragma unroll
            for (int j = 0; j < 8; j++)
                av[j] = sA[m * 68 + ks * 32 + quad * 8 + j];
            make_afrag(av, ah, al);
            mfma1g(g.W2a, ks, w, lane, ah, al, acc);
        }
        #pragma unroll
        for (int r = 0; r < 4; r++)
            sB[(quad * 4 + r) * 68 + w * 16 + m] = acc[r];
    }
    __syncthreads();

    // ---- Phase B: edge buckets (4 per wave), aggr -> sA ----
    {
        int dbase = bb * 16 + w * 4;
        int q0 = (dbase == 0) ? 0 : g.ends_e[dbase - 1];
        int e1 = g.ends_e[dbase], e2 = g.ends_e[dbase + 1];
        int e3 = g.ends_e[dbase + 2], q1 = g.ends_e[dbase + 3];
        if (q0 < 0) q0 = 0; if (q0 > N_EDGES) q0 = N_EDGES;
        if (q1 < q0) q1 = q0; if (q1 > N_EDGES) q1 = N_EDGES;
        if (e1 < q0) e1 = q0; if (e1 > q1) e1 = q1;
        if (e2 < e1) e2 = e1; if (e2 > q1) e2 = q1;
        if (e3 < e2) e3 = e2; if (e3 > q1) e3 = q1;
        float ad0 = sB[(w * 4 + 0) * 68 + lane];
        float ad1 = sB[(w * 4 + 1) * 68 + lane];
        float ad2 = sB[(w * 4 + 2) * 68 + lane];
        float ad3 = sB[(w * 4 + 3) * 68 + lane];
        float s0 = 0.f, s1 = 0.f, s2 = 0.f, s3 = 0.f;
        for (int p = q0; p < q1; p += 8) {
            int ss[8]; float hv[8];
            #pragma unroll
            for (int i = 0; i < 8; i++) {
                int sv = (p + i < q1) ? g.src_s[p + i] : 0;
                if ((unsigned)sv >= N_NODES) sv = 0;
                ss[i] = sv;
            }
            #pragma unroll
            for (int i = 0; i < 8; i++)
                hv[i] = g.Y[(size_t)ss[i] * 64 + lane];
            #pragma unroll
            for (int i = 0; i < 8; i++) {
                int pp = p + i;
                if (pp >= q1) continue;
                float ad = (pp >= e3) ? ad3 : (pp >= e2) ? ad2 : (pp >= e1) ? ad1 : ad0;
                float v = fmaxf(hv[i] + ad, 0.f);
                if (pp < e1) s0 += v;
                else if (pp < e2) s1 += v;
                else if (pp < e3) s2 += v;
                else s3 += v;
            }
        }
        sA[(w * 4 + 0) * 68 + lane] = s0;
        sA[(w * 4 + 1) * 68 + lane] = s1;
        sA[(w * 4 + 2) * 68 + lane] = s2;
        sA[(w * 4 + 3) * 68 + lane] = s3;
    }
    __syncthreads();

    // ---- Phase C1: z = relu([A1 | aggr] @ Wn1 + bn1), nt=w -> sB ----
    {
        float b = g.bn1l[w * 16 + m];
        f4v acc = (f4v){b, b, b, b};
        #pragma unroll
        for (int ks = 0; ks < 2; ks++) {
            ldrow8f(g.A1, row, ks, quad, av);
            make_afrag(av, ah, al);
            mfma1g(g.Wn1l, ks, w, lane, ah, al, acc);
        }
        #pragma unroll
        for (int ks = 0; ks < 2; ks++) {
            #pragma unroll
            for (int j = 0; j < 8; j++)
                av[j] = sA[m * 68 + ks * 32 + quad * 8 + j];
            make_afrag(av, ah, al);
            mfma1g(g.Wn1l + 64 * 64, ks, w, lane, ah, al, acc);
        }
        #pragma unroll
        for (int r = 0; r < 4; r++)
            sB[(quad * 4 + r) * 68 + w * 16 + m] = fmaxf(acc[r], 0.f);
    }
    __syncthreads();

    // ---- Phase C2: h' = z @ Wn2 + bn2 -> global (+sA if has_next) ----
    f4v acc2;
    {
        float b = g.bn2l[w * 16 + m];
        acc2 = (f4v){b, b, b, b};
        #pragma unroll
        for (int ks = 0; ks < 2; ks++) {
            #pragma unroll
            for (int j = 0; j < 8; j++)
                av[j] = sB[m * 68 + ks * 32 + quad * 8 + j];
            make_afrag(av, ah, al);
            mfma1g(g.Wn2l, ks, w, lane, ah, al, acc2);
        }
        #pragma unroll
        for (int r = 0; r < 4; r++)
            NTS(&g.hout[(size_t)(bb * 16 + quad * 4 + r) * 64 + w * 16 + m], acc2[r]);
    }
    if (g.has_next) {
        __syncthreads();  // aggr (sA) fully consumed in C1
        #pragma unroll
        for (int r = 0; r < 4; r++)
            sA[(quad * 4 + r) * 68 + w * 16 + m] = acc2[r];
        __syncthreads();
        float bx = g.b1n[w * 16 + m];
        float by = g.b2n[w * 16 + m];
        f4v aX = (f4v){bx, bx, bx, bx};
        f4v aY = (f4v){by, by, by, by};
        #pragma unroll
        for (int ks = 0; ks < 2; ks++) {
            #pragma unroll
            for (int j = 0; j < 8; j++)
                av[j] = sA[m * 68 + ks * 32 + quad * 8 + j];
            make_afrag(av, ah, al);
            mfma1g(g.W1n, ks, w, lane, ah, al, aX);
            mfma1g(g.W2n, ks, w, lane, ah, al, aY);
        }
        #pragma unroll
        for (int r = 0; r < 4; r++) {
            size_t rr = (size_t)(bb * 16 + quad * 4 + r) * 64 + w * 16 + m;
            NTS(&g.Xn[rr], aX[r]);
            NTS(&g.Yn[rr], aY[r]);
        }
    }
}

// ---------------------------------------------------------------- pool + head
__global__ __launch_bounds__(256) void k_poolhead(
    const float* __restrict__ h, const int* __restrict__ batch,
    const float* __restrict__ Wo1, const float* __restrict__ bo1,
    const float* __restrict__ Wo2, const float* __restrict__ bo2,
    float* __restrict__ out) {
    __shared__ float red[4][64];
    int b = blockIdx.x;
    int lo = 0, hi = N_NODES;
    while (lo < hi) { int mid = (lo + hi) >> 1; if (batch[mid] < b) lo = mid + 1; else hi = mid; }
    int start = lo;
    hi = N_NODES;
    while (lo < hi) { int mid = (lo + hi) >> 1; if (batch[mid] < b + 1) lo = mid + 1; else hi = mid; }
    int end = lo;
    int lane = threadIdx.x & 63;
    int w = threadIdx.x >> 6;
    float s = 0.f;
    for (int n = start + w; n < end; n += 4)
        s += h[(size_t)n * 64 + lane];
    red[w][lane] = s;
    __syncthreads();
    if (w == 0) {
        float tot = red[0][lane] + red[1][lane] + red[2][lane] + red[3][lane];
        float c = (float)(end - start);
        float p = fmaxf(tot / fmaxf(c, 1.0f), 0.f);
        float acc = bo1[lane];
        #pragma unroll
        for (int kk = 0; kk < 64; kk++)
            acc += __shfl(p, kk) * Wo1[kk * 64 + lane];
        float t1 = fmaxf(acc, 0.f);
        float acc2 = (lane < OUT_DIM) ? bo2[lane] : 0.f;
        #pragma unroll
        for (int kk = 0; kk < 64; kk++) {
            float wv = (lane < OUT_DIM) ? Wo2[kk * OUT_DIM + lane] : 0.f;
            acc2 += __shfl(t1, kk) * wv;
        }
        if (lane < OUT_DIM) out[b * OUT_DIM + lane] = acc2;
    }
}

extern "C" void kernel_launch(void* const* d_in, const int* in_sizes, int n_in,
                              void* d_out, int out_size, void* d_ws, size_t ws_size,
                              hipStream_t stream) {
    const int expect[19] = {
        N_NODES * 64, N_EDGES * 6, N_TRI * 6,
        L_LAYERS * 76 * 64, L_LAYERS * 64,
        L_LAYERS * 128 * 64, L_LAYERS * 64,
        L_LAYERS * 128 * 64, L_LAYERS * 64,
        L_LAYERS * 64 * 64, L_LAYERS * 64,
        64 * 64, 64, 64 * OUT_DIM, OUT_DIM,
        2 * N_EDGES, N_TRI, N_TRI, N_NODES
    };

    char* ws = (char*)d_ws;
    float* hA    = (float*)(ws + 0);
    float* hB    = (float*)(ws + 4096000);
    float* X0    = (float*)(ws + 8192000);
    float* Y0    = (float*)(ws + 12288000);
    float* X1    = (float*)(ws + 16384000);
    float* Y1    = (float*)(ws + 20480000);
    int*   cur_t = (int*)(ws + 24576000);
    int*   cur_e = (int*)(ws + 24640000);
    int*   tri_o = (int*)(ws + 24704000);
    int*   k_srt = (int*)(ws + 27264000);
    int*   src_s = (int*)(ws + 29824000);
    const size_t FULL_NEED = 30848000u;

    const int out_n = N_B * OUT_DIM;

    int perm[19];
    bool used[64];
    for (int i = 0; i < 64; i++) used[i] = false;
    int fail_slot = -1;
    for (int i = 0; i < 19; i++) {
        perm[i] = -1;
        for (int jj = 0; jj < n_in && jj < 64; jj++) {
            if (!used[jj] && in_sizes[jj] == expect[i]) { used[jj] = true; perm[i] = jj; break; }
        }
        if (perm[i] < 0 && fail_slot < 0) fail_slot = i;
    }

    if (n_in < 19 || fail_slot >= 0 || ws_size < FULL_NEED) {
        float code = (ws_size < FULL_NEED) ? 40000.0f
                   : (n_in < 19)           ? 50000.0f
                   : 20000.0f + 1000.0f * (float)fail_slot;
        k_fill<<<(out_n + 255) / 256, 256, 0, stream>>>((float*)d_out, code, out_n);
        return;
    }

    const float* x    = (const float*)d_in[perm[0]];
    const float* rbf  = (const float*)d_in[perm[1]];
    const float* cbf  = (const float*)d_in[perm[2]];
    const float* W1   = (const float*)d_in[perm[3]];
    const float* b1   = (const float*)d_in[perm[4]];
    const float* W2   = (const float*)d_in[perm[5]];
    const float* b2   = (const float*)d_in[perm[6]];
    const float* Wn1  = (const float*)d_in[perm[7]];
    const float* bn1  = (const float*)d_in[perm[8]];
    const float* Wn2  = (const float*)d_in[perm[9]];
    const float* bn2  = (const float*)d_in[perm[10]];
    const float* Wo1  = (const float*)d_in[perm[11]];
    const float* bo1  = (const float*)d_in[perm[12]];
    const float* Wo2  = (const float*)d_in[perm[13]];
    const float* bo2  = (const float*)d_in[perm[14]];
    const int* edge_index = (const int*)d_in[perm[15]];
    const int* k_idx = (const int*)d_in[perm[16]];
    const int* j_idx = (const int*)d_in[perm[17]];
    const int* batch = (const int*)d_in[perm[18]];

    const int TB = (N_TRI + 255) / 256;
    const int EB = (N_EDGES + 255) / 256;

    // ---- setup: 4 regular dispatches ----
    k_setup<<<64, 256, 0, stream>>>(cur_t);
    k_hist2<<<TB + EB, 256, 0, stream>>>(j_idx, edge_index, cur_t, cur_e);
    k_scan2<<<2, 256, 0, stream>>>(cur_t, cur_e);
    k_scatter2<<<TB + EB, 256, 0, stream>>>(j_idx, k_idx, edge_index,
                                            cur_t, cur_e, tri_o, k_srt, src_s);
    // layer-0 X/Y (FIXED: block per tile)
    k_lin2out<<<N_NODES / 16, 256, 0, stream>>>(x, W1, b1, W2, b2, X0, Y0);

    // ---- 3x k_meg ----
    const float* hc = x;
    float* hout = hA;
    float* Xc = X0; float* Yc = Y0;
    float* Xn = X1; float* Yn = Y1;
    for (int l = 0; l < L_LAYERS; l++) {
        MegA g;
        g.ends_t = cur_t; g.tri_o = tri_o; g.k_srt = k_srt;
        g.ends_e = cur_e; g.src_s = src_s;
        g.X = Xc; g.Y = Yc;
        g.rbf = rbf; g.cbf = cbf; g.A1 = hc;
        g.W1l  = W1 + (size_t)l * 76 * 64;
        g.W2a  = W2 + (size_t)l * 128 * 64 + 64 * 64;
        g.Wn1l = Wn1 + (size_t)l * 128 * 64;
        g.bn1l = bn1 + (size_t)l * 64;
        g.Wn2l = Wn2 + (size_t)l * 64 * 64;
        g.bn2l = bn2 + (size_t)l * 64;
        g.has_next = (l < L_LAYERS - 1) ? 1 : 0;
        g.W1n = W1 + (size_t)(l + 1) * 76 * 64;
        g.b1n = b1 + (size_t)(l + 1) * 64;
        g.W2n = W2 + (size_t)(l + 1) * 128 * 64;
        g.b2n = b2 + (size_t)(l + 1) * 64;
        g.hout = hout; g.Xn = Xn; g.Yn = Yn;
        k_meg<<<N_NODES / 16, 256, 0, stream>>>(g);
        hc = hout;
        hout = (hout == hA) ? hB : hA;
        float* t;
        t = Xc; Xc = Xn; Xn = t;
        t = Yc; Yc = Yn; Yn = t;
    }

    // ---- pool + head ----
    k_poolhead<<<N_B, 256, 0, stream>>>(hA, batch, Wo1, bo1, Wo2, bo2, (float*)d_out);
}